// Round 1
// baseline (574.177 us; speedup 1.0000x reference)
//
#include <hip/hip_runtime.h>
#include <math.h>

// Chamfer distance, B=4, N=M=8192, D=3, fp32.
// out[b] = mean_n min_m d2(a_n, b_m) + mean_m min_n d2(b_m, a_n)
// d2 = a2 + (b2 - 2 a.b); minimize (b2 - 2 a.b) per thread, add a2 + clamp after.

#define BATCH   4
#define NPTS    8192
#define THREADS 256
#define TILE    2048

__global__ void zero_out_kernel(float* out) {
    if (threadIdx.x < BATCH) out[threadIdx.x] = 0.0f;
}

__global__ __launch_bounds__(THREADS) void chamfer_kernel(
        const float* __restrict__ pc1,
        const float* __restrict__ pc2,
        float* __restrict__ out) {
    // grid = 2 (dir) * BATCH * (NPTS/THREADS)
    const int chunks = NPTS / THREADS;          // 32
    int bid   = blockIdx.x;
    int chunk = bid % chunks;
    int batch = (bid / chunks) % BATCH;
    int dir   = bid / (chunks * BATCH);

    const float* a = (dir == 0) ? pc1 : pc2;
    const float* b = (dir == 0) ? pc2 : pc1;
    a += (size_t)batch * NPTS * 3;
    b += (size_t)batch * NPTS * 3;

    const int n = chunk * THREADS + threadIdx.x;
    const float ax = a[n * 3 + 0];
    const float ay = a[n * 3 + 1];
    const float az = a[n * 3 + 2];
    const float cx = -2.0f * ax;
    const float cy = -2.0f * ay;
    const float cz = -2.0f * az;

    __shared__ float4 sb[TILE];

    float best = 3.4e38f;
    for (int base = 0; base < NPTS; base += TILE) {
        // stage tile: (x, y, z, b2) per point
        for (int i = threadIdx.x; i < TILE; i += THREADS) {
            const float x = b[(base + i) * 3 + 0];
            const float y = b[(base + i) * 3 + 1];
            const float z = b[(base + i) * 3 + 2];
            sb[i] = make_float4(x, y, z, fmaf(x, x, fmaf(y, y, z * z)));
        }
        __syncthreads();

        #pragma unroll 8
        for (int j = 0; j < TILE; ++j) {
            const float4 p = sb[j];
            float t = fmaf(cx, p.x, p.w);
            t = fmaf(cy, p.y, t);
            t = fmaf(cz, p.z, t);
            best = fminf(best, t);
        }
        __syncthreads();
    }

    const float a2 = fmaf(ax, ax, fmaf(ay, ay, az * az));
    float d2 = fmaxf(best + a2, 0.0f);

    // block sum-reduction of d2
    #pragma unroll
    for (int off = 32; off > 0; off >>= 1)
        d2 += __shfl_down(d2, off, 64);

    __shared__ float wsum[THREADS / 64];
    if ((threadIdx.x & 63) == 0) wsum[threadIdx.x >> 6] = d2;
    __syncthreads();

    if (threadIdx.x == 0) {
        float s = 0.0f;
        #pragma unroll
        for (int w = 0; w < THREADS / 64; ++w) s += wsum[w];
        atomicAdd(&out[batch], s * (1.0f / (float)NPTS));
    }
}

extern "C" void kernel_launch(void* const* d_in, const int* in_sizes, int n_in,
                              void* d_out, int out_size, void* d_ws, size_t ws_size,
                              hipStream_t stream) {
    const float* pc1 = (const float*)d_in[0];
    const float* pc2 = (const float*)d_in[1];
    float* out = (float*)d_out;

    zero_out_kernel<<<1, 64, 0, stream>>>(out);

    const int blocks = 2 * BATCH * (NPTS / THREADS);   // 256
    chamfer_kernel<<<blocks, THREADS, 0, stream>>>(pc1, pc2, out);
}

// Round 2
// 102.191 us; speedup vs baseline: 5.6186x; 5.6186x over previous
//
#include <hip/hip_runtime.h>
#include <math.h>

// Chamfer distance, B=4, N=M=8192, D=3, fp32, out[b] = mean_n min_m d2 + mean_m min_n d2.
// d2 = a2 + t, t = b2 - 2 a.b ; minimize t per n (a2 const per n), add a2 + clamp at the end.
//
// 3 kernels:
//  A: pack (x,y,z,|p|^2) float4 into ws; init atomicMin keys; zero out.
//  B: grid (dir,batch,nchunk,slice): P=8 n-points/thread, LDS-staged m-slice,
//     partial min over slice, ordered-int atomicMin into ws.
//  C: decode min key, add a2 (from pack.w), clamp, block-reduce, atomicAdd mean.

#define BATCH   4
#define NPTS    8192
#define THREADS 256
#define P       8                    // n-points per thread
#define SLICES  32                   // m-slices
#define SLICE   (NPTS / SLICES)      // 256 m-points per slice (== THREADS)
#define NCHUNK  (THREADS * P)        // 2048 n-points per block
#define NBLK    (NPTS / NCHUNK)      // 4 n-chunks

// monotone float->uint map: unsigned order == float order
__device__ __forceinline__ unsigned encode_f32(float f) {
    unsigned b = __float_as_uint(f);
    return (b & 0x80000000u) ? ~b : (b | 0x80000000u);
}
__device__ __forceinline__ float decode_f32(unsigned k) {
    unsigned b = (k & 0x80000000u) ? (k & 0x7FFFFFFFu) : ~k;
    return __uint_as_float(b);
}

__global__ __launch_bounds__(THREADS) void pack_kernel(
        const float* __restrict__ pc1, const float* __restrict__ pc2,
        float4* __restrict__ pack, unsigned* __restrict__ mink,
        float* __restrict__ out) {
    int idx = blockIdx.x * THREADS + threadIdx.x;     // 0 .. 2*B*N-1
    int c   = idx >> 15;                              // cloud: 0=pc1, 1=pc2
    int rem = idx & 32767;                            // batch*N + m (contiguous)
    const float* src = (c == 0 ? pc1 : pc2) + (size_t)rem * 3;
    float x = src[0], y = src[1], z = src[2];
    pack[idx] = make_float4(x, y, z, fmaf(x, x, fmaf(y, y, z * z)));
    mink[idx] = 0xFFFFFFFFu;                          // +inf key
    if (idx < BATCH) out[idx] = 0.0f;
}

__global__ __launch_bounds__(THREADS) void chamfer_min_kernel(
        const float4* __restrict__ pack, unsigned* __restrict__ mink) {
    int bid    = blockIdx.x;                 // 1024 = 2*4*4*32
    int s      = bid & (SLICES - 1);
    int nchunk = (bid >> 5) & (NBLK - 1);
    int batch  = (bid >> 7) & (BATCH - 1);
    int dir    = bid >> 9;

    const float4* bp = pack + ((size_t)(dir ^ 1) * BATCH + batch) * NPTS + s * SLICE;
    const float4* ap = pack + ((size_t)dir * BATCH + batch) * NPTS + nchunk * NCHUNK;

    __shared__ float4 sb[SLICE];
    sb[threadIdx.x] = bp[threadIdx.x];       // SLICE == THREADS: one float4/lane

    float cx[P], cy[P], cz[P], best[P];
    #pragma unroll
    for (int k = 0; k < P; ++k) {
        float4 a = ap[k * THREADS + threadIdx.x];
        cx[k] = -2.0f * a.x;
        cy[k] = -2.0f * a.y;
        cz[k] = -2.0f * a.z;
        best[k] = 3.4e38f;
    }
    __syncthreads();

    #pragma unroll 4
    for (int j = 0; j < SLICE; j += 2) {
        const float4 p0 = sb[j];
        const float4 p1 = sb[j + 1];
        #pragma unroll
        for (int k = 0; k < P; ++k) {
            float t0 = fmaf(cx[k], p0.x, fmaf(cy[k], p0.y, fmaf(cz[k], p0.z, p0.w)));
            float t1 = fmaf(cx[k], p1.x, fmaf(cy[k], p1.y, fmaf(cz[k], p1.z, p1.w)));
            best[k] = fminf(fminf(best[k], t0), t1);   // -> v_min3_f32
        }
    }

    unsigned* mk = mink + ((size_t)dir * BATCH + batch) * NPTS + nchunk * NCHUNK;
    #pragma unroll
    for (int k = 0; k < P; ++k)
        atomicMin(&mk[k * THREADS + threadIdx.x], encode_f32(best[k]));
}

__global__ __launch_bounds__(THREADS) void finalize_kernel(
        const float4* __restrict__ pack, const unsigned* __restrict__ mink,
        float* __restrict__ out) {
    int bid   = blockIdx.x;                  // 256 = 2*4*32
    int chunk = bid & 31;
    int batch = (bid >> 5) & (BATCH - 1);
    int dir   = bid >> 7;
    int n     = chunk * THREADS + threadIdx.x;
    size_t base = ((size_t)dir * BATCH + batch) * NPTS;   // a-cloud == dir

    float t  = decode_f32(mink[base + n]);
    float a2 = pack[base + n].w;
    float d2 = fmaxf(t + a2, 0.0f);

    #pragma unroll
    for (int off = 32; off > 0; off >>= 1)
        d2 += __shfl_down(d2, off, 64);

    __shared__ float wsum[THREADS / 64];
    if ((threadIdx.x & 63) == 0) wsum[threadIdx.x >> 6] = d2;
    __syncthreads();

    if (threadIdx.x == 0) {
        float ssum = 0.0f;
        #pragma unroll
        for (int w = 0; w < THREADS / 64; ++w) ssum += wsum[w];
        atomicAdd(&out[batch], ssum * (1.0f / (float)NPTS));
    }
}

extern "C" void kernel_launch(void* const* d_in, const int* in_sizes, int n_in,
                              void* d_out, int out_size, void* d_ws, size_t ws_size,
                              hipStream_t stream) {
    const float* pc1 = (const float*)d_in[0];
    const float* pc2 = (const float*)d_in[1];
    float* out = (float*)d_out;

    float4*   pack = (float4*)d_ws;                                   // 1 MB
    unsigned* mink = (unsigned*)((char*)d_ws +
                       (size_t)2 * BATCH * NPTS * sizeof(float4));    // 256 KB

    pack_kernel<<<(2 * BATCH * NPTS) / THREADS, THREADS, 0, stream>>>(pc1, pc2, pack, mink, out);
    chamfer_min_kernel<<<2 * BATCH * NBLK * SLICES, THREADS, 0, stream>>>(pack, mink);
    finalize_kernel<<<2 * BATCH * (NPTS / THREADS), THREADS, 0, stream>>>(pack, mink, out);
}

// Round 3
// 100.396 us; speedup vs baseline: 5.7191x; 1.0179x over previous
//
#include <hip/hip_runtime.h>
#include <math.h>

// Chamfer distance, B=4, N=M=8192, D=3, fp32.
// t = |b|^2 - 2 a.b minimized per n over m (a^2 const, added after min).
// Packed fp32 (v_pk_fma_f32): 2 m-points per FMA; m-tile staged SoA-pairs in LDS
// with -2 pre-folded: x' = -2x, y' = -2y, z' = -2z, w = |b|^2.
// Kernels: init (mink=+inf keys, out=0) -> chamfer_min (atomicMin ordered-int keys)
//          -> finalize (decode, +a^2, clamp, mean, atomicAdd).

#define BATCH   4
#define NPTS    8192
#define THREADS 256
#define P       16                   // n-points per thread
#define SLICES  32                   // m-slices
#define SLICE   (NPTS / SLICES)      // 256
#define NCHUNK  (THREADS * P)        // 4096
#define NBLK    (NPTS / NCHUNK)      // 2

typedef float v2f __attribute__((ext_vector_type(2)));

__device__ __forceinline__ unsigned encode_f32(float f) {
    unsigned b = __float_as_uint(f);
    return (b & 0x80000000u) ? ~b : (b | 0x80000000u);
}
__device__ __forceinline__ float decode_f32(unsigned k) {
    unsigned b = (k & 0x80000000u) ? (k & 0x7FFFFFFFu) : ~k;
    return __uint_as_float(b);
}

__global__ __launch_bounds__(THREADS) void init_kernel(
        unsigned* __restrict__ mink, float* __restrict__ out) {
    int idx = blockIdx.x * THREADS + threadIdx.x;   // 0 .. 2*B*N-1
    mink[idx] = 0xFFFFFFFFu;
    if (idx < BATCH) out[idx] = 0.0f;
}

__global__ __launch_bounds__(THREADS) void chamfer_min_kernel(
        const float* __restrict__ pc1, const float* __restrict__ pc2,
        unsigned* __restrict__ mink) {
    int bid    = blockIdx.x;                 // 512 = 2*4*2*32
    int s      = bid & (SLICES - 1);
    int nchunk = (bid >> 5) & (NBLK - 1);
    int batch  = (bid >> 6) & (BATCH - 1);
    int dir    = bid >> 8;

    const float* acld = dir ? pc2 : pc1;
    const float* bcld = dir ? pc1 : pc2;
    const float* ab = acld + ((size_t)batch * NPTS + (size_t)nchunk * NCHUNK) * 3;
    const float* bb = bcld + ((size_t)batch * NPTS + (size_t)s * SLICE) * 3;

    // SoA pair layout: sxy[4p + {0,1}] = x'(2p), x'(2p+1); sxy[4p + {2,3}] = y' pair
    __shared__ float sxy[SLICE * 2];
    __shared__ float szw[SLICE * 2];

    const int t = threadIdx.x;
    {
        float x = bb[3 * t + 0], y = bb[3 * t + 1], z = bb[3 * t + 2];
        float w = fmaf(x, x, fmaf(y, y, z * z));
        int p = t >> 1, h = t & 1;
        sxy[4 * p + h]     = -2.0f * x;
        sxy[4 * p + 2 + h] = -2.0f * y;
        szw[4 * p + h]     = -2.0f * z;
        szw[4 * p + 2 + h] = w;
    }

    v2f ax2[P], ay2[P], az2[P];
    float best[P];
    #pragma unroll
    for (int k = 0; k < P; ++k) {
        const float* ap = ab + 3 * (k * THREADS + t);
        float x = ap[0], y = ap[1], z = ap[2];
        ax2[k] = (v2f){x, x};
        ay2[k] = (v2f){y, y};
        az2[k] = (v2f){z, z};
        best[k] = 3.4e38f;
    }
    __syncthreads();

    const float4* pxy = (const float4*)sxy;
    const float4* pzw = (const float4*)szw;
    #pragma unroll 2
    for (int jp = 0; jp < SLICE / 2; ++jp) {
        const float4 A = pxy[jp];               // x0 x1 y0 y1
        const float4 B = pzw[jp];               // z0 z1 w0 w1
        const v2f xs = (v2f){A.x, A.y};
        const v2f ys = (v2f){A.z, A.w};
        const v2f zs = (v2f){B.x, B.y};
        const v2f ws = (v2f){B.z, B.w};
        #pragma unroll
        for (int k = 0; k < P; ++k) {
            v2f tt = __builtin_elementwise_fma(az2[k], zs, ws);
            tt = __builtin_elementwise_fma(ay2[k], ys, tt);
            tt = __builtin_elementwise_fma(ax2[k], xs, tt);
            best[k] = fminf(fminf(best[k], tt.x), tt.y);   // v_min3_f32
        }
    }

    unsigned* mk = mink + ((size_t)dir * BATCH + batch) * NPTS + (size_t)nchunk * NCHUNK;
    #pragma unroll
    for (int k = 0; k < P; ++k)
        atomicMin(&mk[k * THREADS + t], encode_f32(best[k]));
}

__global__ __launch_bounds__(THREADS) void finalize_kernel(
        const float* __restrict__ pc1, const float* __restrict__ pc2,
        const unsigned* __restrict__ mink, float* __restrict__ out) {
    int bid   = blockIdx.x;                  // 256 = 2*4*32
    int chunk = bid & 31;
    int batch = (bid >> 5) & (BATCH - 1);
    int dir   = bid >> 7;
    int n     = chunk * THREADS + threadIdx.x;

    const float* acld = dir ? pc2 : pc1;
    const float* ap = acld + ((size_t)batch * NPTS + n) * 3;
    float x = ap[0], y = ap[1], z = ap[2];
    float a2 = fmaf(x, x, fmaf(y, y, z * z));

    float tmin = decode_f32(mink[((size_t)dir * BATCH + batch) * NPTS + n]);
    float d2 = fmaxf(tmin + a2, 0.0f);

    #pragma unroll
    for (int off = 32; off > 0; off >>= 1)
        d2 += __shfl_down(d2, off, 64);

    __shared__ float wsum[THREADS / 64];
    if ((threadIdx.x & 63) == 0) wsum[threadIdx.x >> 6] = d2;
    __syncthreads();

    if (threadIdx.x == 0) {
        float ssum = 0.0f;
        #pragma unroll
        for (int w = 0; w < THREADS / 64; ++w) ssum += wsum[w];
        atomicAdd(&out[batch], ssum * (1.0f / (float)NPTS));
    }
}

extern "C" void kernel_launch(void* const* d_in, const int* in_sizes, int n_in,
                              void* d_out, int out_size, void* d_ws, size_t ws_size,
                              hipStream_t stream) {
    const float* pc1 = (const float*)d_in[0];
    const float* pc2 = (const float*)d_in[1];
    float* out = (float*)d_out;
    unsigned* mink = (unsigned*)d_ws;        // 2*B*N * 4 bytes = 256 KB

    init_kernel<<<(2 * BATCH * NPTS) / THREADS, THREADS, 0, stream>>>(mink, out);
    chamfer_min_kernel<<<2 * BATCH * NBLK * SLICES, THREADS, 0, stream>>>(pc1, pc2, mink);
    finalize_kernel<<<2 * BATCH * (NPTS / THREADS), THREADS, 0, stream>>>(pc1, pc2, mink, out);
}